// Round 13
// baseline (499.273 us; speedup 1.0000x reference)
//
#include <hip/hip_runtime.h>

// MoE MLP (B=2,T=2048,H=1024,E=8,F=4096,K=2), fp32 in/out.
// route -> group tokens by expert -> fused grouped GEMMs (128x128 tile,
// 8 waves of 64x32, acc=32 -> register room for TWO B prefetch sets;
// As x3 + Bs x2 = 80KB LDS, 2 blocks/CU = 16 waves; every vmcnt wait
// targets loads issued a FULL step earlier; one barrier per step) ->
// weighted combine.  G2 = split-K2 with bf16 partials.

typedef unsigned short ushort_t;
typedef __attribute__((ext_vector_type(2))) float f32x2;
typedef __attribute__((ext_vector_type(4))) unsigned int u32x4;
typedef __attribute__((ext_vector_type(4))) unsigned short u16x4;
typedef __attribute__((ext_vector_type(4))) float f32x4;
typedef __attribute__((ext_vector_type(8))) __bf16 bf16x8;

#define NTOK 4096   // B*T
#define HD   1024
#define FD   4096
#define NE   8
#define NKTOT 8192  // NTOK * TOP_K

__device__ __forceinline__ ushort_t f2bf(float f) {
  unsigned u = __builtin_bit_cast(unsigned, f);
  u += 0x7fffu + ((u >> 16) & 1u);   // RNE
  return (ushort_t)(u >> 16);
}
__device__ __forceinline__ unsigned pk2(float a, float b) {
  unsigned r;
  asm("v_cvt_pk_bf16_f32 %0, %1, %2" : "=v"(r) : "v"(a), "v"(b));
  return r;  // lo = bf16(a), hi = bf16(b), RNE
}
__device__ __forceinline__ float bf2f(ushort_t u) {
  unsigned v = ((unsigned)u) << 16;
  return __builtin_bit_cast(float, v);
}
__device__ __forceinline__ bf16x8 frag_ld(const void* p) {
  u32x4 v = *reinterpret_cast<const u32x4*>(p);
  return __builtin_bit_cast(bf16x8, v);
}

#define GLOAD16(g, l) __builtin_amdgcn_global_load_lds(                         \
    (const __attribute__((address_space(1))) unsigned int*)(g),                 \
    (__attribute__((address_space(3))) unsigned int*)(l), 16, 0, 0)

#define WAITVM(N) asm volatile("s_waitcnt vmcnt(" #N ")" ::: "memory")
#define BARRIER() do { asm volatile("s_waitcnt lgkmcnt(0)" ::: "memory");       \
                       __builtin_amdgcn_s_barrier(); } while (0)

// ---------------------------------------------------------------- init
__global__ void init_k(int* counts) {
  if (threadIdx.x < NE) counts[threadIdx.x] = 0;
}

// ------------------------------------------- router (+ fused x->bf16 conv)
__global__ void router_k(const float* __restrict__ x, const float* __restrict__ rw,
                         ushort_t* __restrict__ Xbf,
                         float* __restrict__ tokP, int* __restrict__ counts,
                         int* __restrict__ tk_e, int* __restrict__ tk_s,
                         float* __restrict__ tk_w) {
  const int w = threadIdx.x >> 6, l = threadIdx.x & 63;
  const int t = blockIdx.x * 4 + w;
  const float* xr = x + (size_t)t * HD;
  ushort_t* xo = Xbf + (size_t)t * HD;
  float acc[NE];
#pragma unroll
  for (int e = 0; e < NE; ++e) acc[e] = 0.f;
  for (int it = 0; it < HD / 64; ++it) {
    const int h = l + it * 64;
    const float xv = xr[h];
    xo[h] = f2bf(xv);
#pragma unroll
    for (int e = 0; e < NE; ++e) acc[e] = fmaf(xv, rw[e * HD + h], acc[e]);
  }
#pragma unroll
  for (int e = 0; e < NE; ++e) {
#pragma unroll
    for (int s = 32; s > 0; s >>= 1) acc[e] += __shfl_xor(acc[e], s, 64);
  }
  float m = acc[0];
#pragma unroll
  for (int e = 1; e < NE; ++e) m = fmaxf(m, acc[e]);
  float ssum = 0.f;
  float p[NE];
#pragma unroll
  for (int e = 0; e < NE; ++e) { p[e] = expf(acc[e] - m); ssum += p[e]; }
  const float inv = 1.f / ssum;
  if (l < NE) tokP[(size_t)t * NE + l] = p[l] * inv;

  if (l == 0) {
    int i0 = 0; float v0 = acc[0];
#pragma unroll
    for (int e = 1; e < NE; ++e) if (acc[e] > v0) { v0 = acc[e]; i0 = e; }
    int i1 = -1; float v1 = -3.4e38f;
#pragma unroll
    for (int e = 0; e < NE; ++e) if (e != i0 && acc[e] > v1) { v1 = acc[e]; i1 = e; }
    const float w0 = 1.f / (1.f + expf(v1 - v0));
    const int s0 = atomicAdd(&counts[i0], 1);
    const int s1 = atomicAdd(&counts[i1], 1);
    tk_e[2 * t] = i0;     tk_s[2 * t] = s0;     tk_w[2 * t] = w0;
    tk_e[2 * t + 1] = i1; tk_s[2 * t + 1] = s1; tk_w[2 * t + 1] = 1.f - w0;
  }
}

// ------------------------------------------- offsets + aux loss + tail out
__global__ void finalize_k(const float* __restrict__ tokP, const int* __restrict__ counts,
                           int* __restrict__ offsets, float* __restrict__ out_tail) {
  __shared__ float red[16][8];
  const int tid = threadIdx.x;  // 1024
  f32x4 a0 = {0.f, 0.f, 0.f, 0.f}, a1 = {0.f, 0.f, 0.f, 0.f};
#pragma unroll
  for (int k = 0; k < 4; ++k) {
    const float* p = tokP + ((size_t)tid * 4 + k) * 8;
    a0 += *reinterpret_cast<const f32x4*>(p);
    a1 += *reinterpret_cast<const f32x4*>(p + 4);
  }
#pragma unroll
  for (int s = 1; s < 64; s <<= 1) {
#pragma unroll
    for (int c = 0; c < 4; ++c) {
      a0[c] += __shfl_xor(a0[c], s, 64);
      a1[c] += __shfl_xor(a1[c], s, 64);
    }
  }
  if ((tid & 63) == 0) {
    const int wv = tid >> 6;
#pragma unroll
    for (int c = 0; c < 4; ++c) { red[wv][c] = a0[c]; red[wv][4 + c] = a1[c]; }
  }
  __syncthreads();
  if (tid == 0) {
    float P[8];
    for (int c = 0; c < 8; ++c) {
      float s = 0.f;
      for (int q = 0; q < 16; ++q) s += red[q][c];
      P[c] = s * (1.f / NTOK);
    }
    int off = 0; float aux = 0.f;
    for (int q = 0; q < NE; ++q) { offsets[q] = off; off += counts[q]; }
    for (int q = 0; q < NE; ++q) aux += ((float)counts[q] / (float)NKTOT) * P[q];
    out_tail[0] = (float)NE * aux;
    out_tail[1] = 0.f;
  }
}

// ---------------------------------------------------------------- slots
__global__ void build_slots_k(const int* __restrict__ tk_e, const int* __restrict__ tk_s,
                              const int* __restrict__ offsets, int* __restrict__ slot_token) {
  const int i = blockIdx.x * 256 + threadIdx.x;  // < NKTOT
  const int e = tk_e[i];
  slot_token[offsets[e] + tk_s[i]] = i >> 1;
}

// ------ fused grouped GEMM: 128x128, 8 waves, 2-deep both operands ---------
// 512 thr = 8 waves (2M x 4N, 64x32 each; acc = 8 x f32x4 = 32 regs).
// LDS 80KB -> 2 blocks/CU (16 waves):
//   As[3][128r][64k] bf16 (3x16KB): gload_lds 2 steps ahead; chunk swizzle
//     slot' = slot ^ (row&7) via pre-swizzled global src (r5-r12 proven).
//   Bs[2][128n][64k] bf16 (2x16KB): slot' = chunk ^ ((n>>1)&7) (r7-r12
//     proven conflict-free both sides).
// B regs: 2 sets x 8 f32x2 (lane owns n={2l,2l+1}, k-rows 8w..8w+7), issued
// 2 steps ahead.  Queue-exact waits per step t:
//   issueB(t+2); stageA(t+2); compute(t);
//   vmcnt(12) [B(t+1) done, full-step flight]; writeB(t+1)->Bs[(t+1)&1];
//   vmcnt(10) [A(t+1) done]; BARRIER.    (tail: vmcnt 2 / 0)
// G1: mid = gelu(X@w1+b1) bf16.  G2: bf16 k-slice partials (ks=2, K=2048).
template <bool IS_G1>
__global__ __launch_bounds__(512, 4) void moe_fused(
    const ushort_t* __restrict__ A, const float* __restrict__ W,
    const float* __restrict__ bias,
    const int* __restrict__ counts, const int* __restrict__ offsets,
    const int* __restrict__ slot_token,
    ushort_t* __restrict__ midout, ushort_t* __restrict__ ybuf) {
  constexpr int KDF = IS_G1 ? HD : FD;   // A row stride (elems)
  constexpr int WST = IS_G1 ? FD : HD;   // W row stride (floats)
  constexpr int NSTEP = IS_G1 ? 16 : 32;
  const int id = blockIdx.x;
  const int e = id & 7;                  // XCD pin
  const int q = id >> 3;
  const int ty = q % 10;
  const int r = q / 10;
  const int np = IS_G1 ? r : (r >> 1);
  const int ks = IS_G1 ? 0 : (r & 1);
  const int n0 = np * 128;
  const int KB = ks * 2048;              // k window base (elems)
  const int cnt = counts[e];
  if (ty * 128 >= cnt) return;
  const int off = offsets[e];
  const int pos0 = off + ty * 128;
  const int rr = cnt - ty * 128;
  const int rows_rem = rr < 128 ? rr : 128;

  // ushort idx: As[b] at b*8192 (b=0..2); Bs[b] at 24576 + b*8192.  80 KB.
  __shared__ __align__(16) ushort_t lds[40960];

  const int tid = threadIdx.x;
  const int w = tid >> 6, l = tid & 63;
  const int wr = w >> 2, wcn = w & 3;    // 2 (M) x 4 (N) waves, 64x32 each

  // ---- A staging (pre-swizzled source, linear LDS dest)
  const int sw = (((l & 7) ^ ((l >> 3) & 7)) << 4);
  const char* ab[2];
#pragma unroll
  for (int c = 0; c < 2; ++c) {
    const int row = c * 64 + w * 8 + (l >> 3);
    int pos = pos0 + row; if (pos > NKTOT - 1) pos = NKTOT - 1;
    const size_t ar = IS_G1 ? (size_t)slot_token[pos] : (size_t)pos;
    ab[c] = (const char*)A + (ar * KDF + KB) * 2 + sw;
  }

  // ---- B source: lane owns n cols {2l, 2l+1}, k-rows 8w .. 8w+7
  const float* wB = W + (size_t)e * ((size_t)HD * FD) +
                    ((size_t)KB + 8 * w) * WST + n0 + 2 * l;

  f32x4 acc[4][2] = {};
  f32x2 R0[8], R1[8];

  auto stageA = [&](int tt, int buf) {
#pragma unroll
    for (int c = 0; c < 2; ++c)
      GLOAD16(ab[c] + tt * 128, &lds[buf * 8192 + (c * 64 + w * 8) * 64]);
  };
  auto issueB = [&](int tt, f32x2 (&R)[8]) {
    const float* p = wB + (size_t)tt * 64 * WST;
#pragma unroll
    for (int i = 0; i < 8; ++i)
      R[i] = *reinterpret_cast<const f32x2*>(p + (size_t)i * WST);
  };
  auto writeB = [&](int buf, const f32x2 (&R)[8]) {
    // rows n=2l, 2l+1; k-chunk w at swizzled slot w ^ ((n>>1)&7) = w ^ (l&7)
    ushort_t* d = &lds[24576 + buf * 8192 + (2 * l) * 64 + ((w ^ (l & 7)) << 3)];
    u32x4 v;
    v.x = pk2(R[0].x, R[1].x); v.y = pk2(R[2].x, R[3].x);
    v.z = pk2(R[4].x, R[5].x); v.w = pk2(R[6].x, R[7].x);
    *reinterpret_cast<u32x4*>(d) = v;
    v.x = pk2(R[0].y, R[1].y); v.y = pk2(R[2].y, R[3].y);
    v.z = pk2(R[4].y, R[5].y); v.w = pk2(R[6].y, R[7].y);
    *reinterpret_cast<u32x4*>(d + 64) = v;
  };
  auto compute = [&](int abuf, int bbuf) {
    const ushort_t* Ab = &lds[abuf * 8192];
    const ushort_t* Bb = &lds[24576 + bbuf * 8192];
    const int arow = wr * 64 + (l & 15);
    const int brow = wcn * 32 + (l & 15);
    const int ax = l & 7;
    const int bx = (l >> 1) & 7;
#pragma unroll
    for (int kk = 0; kk < 2; ++kk) {
      const int kc = kk * 4 + (l >> 4);
      bf16x8 afr[4];
#pragma unroll
      for (int mm = 0; mm < 4; ++mm)
        afr[mm] = frag_ld(&Ab[(arow + mm * 16) * 64 + ((kc ^ ax) << 3)]);
      __builtin_amdgcn_s_setprio(1);
#pragma unroll
      for (int nn = 0; nn < 2; ++nn) {
        const bf16x8 bfr = frag_ld(&Bb[(brow + nn * 16) * 64 + ((kc ^ bx) << 3)]);
#pragma unroll
        for (int mm = 0; mm < 4; ++mm)
          acc[mm][nn] = __builtin_amdgcn_mfma_f32_16x16x32_bf16(
              afr[mm], bfr, acc[mm][nn], 0, 0, 0);
      }
      __builtin_amdgcn_s_setprio(0);
    }
  };

  // ---- prologue.  Queue: B0:8 A0:2 B1:8 A1:2 = 20.
  issueB(0, R0);
  stageA(0, 0);
  issueB(1, R1);
  stageA(1, 1);
  WAITVM(12);                  // drain B0
  writeB(0, R0);
  WAITVM(10);                  // drain A0
  BARRIER();

  // ---- main loop: one barrier per step, queue-exact counted waits.
  for (int t = 0; t < NSTEP; ++t) {
    const int bb = t & 1;
    if (t + 2 < NSTEP) {
      if (bb == 0) issueB(t + 2, R0); else issueB(t + 2, R1);
      stageA(t + 2, (t + 2) % 3);
    }
    __builtin_amdgcn_sched_barrier(0);   // keep issues ahead of compute
    compute(t % 3, bb);
    if (t + 2 < NSTEP)          { WAITVM(12); }  // B(t+1) landed
    else if (t == NSTEP - 2)    { WAITVM(2);  }
    if (t + 1 < NSTEP) { if (bb == 0) writeB(1, R1); else writeB(0, R0); }
    if (t + 2 < NSTEP)          { WAITVM(10); }  // A(t+1) landed
    else if (t == NSTEP - 2)    { WAITVM(0);  }
    BARRIER();                            // tile t+1 ready everywhere
  }

  // ---- epilogue: acc -> bf16 via LDS repack, coalesced 16B row stores.
  // C/D: col = l&15, row = 4*(l>>4)+j within each 16x16 frag.
  {
    const int lr4 = (l >> 4) * 4, lc = l & 15;
#pragma unroll
    for (int nn = 0; nn < 2; ++nn) {
      const int col = wcn * 32 + nn * 16 + lc;
      const float bv = IS_G1 ? bias[(size_t)e * FD + n0 + col] : 0.f;
#pragma unroll
      for (int mm = 0; mm < 4; ++mm) {
        const int rb = wr * 64 + mm * 16 + lr4;
#pragma unroll
        for (int j = 0; j < 4; ++j) {
          float v = acc[mm][nn][j] + bv;
          if (IS_G1) v = 0.5f * v * (1.0f + erff(v * 0.70710678118654752f));
          lds[(rb + j) * 128 + col] = f2bf(v);
        }
      }
    }
    BARRIER();
#pragma unroll
    for (int p = 0; p < 4; ++p) {
      const int idx = p * 4096 + tid * 8;
      const int row = idx >> 7;
      const int col = idx & 127;
      if (row < rows_rem) {
        const u32x4 v = *reinterpret_cast<const u32x4*>(&lds[idx]);
        if (IS_G1)
          *reinterpret_cast<u32x4*>(&midout[(size_t)(pos0 + row) * FD + n0 + col]) = v;
        else
          *reinterpret_cast<u32x4*>(
              &ybuf[((size_t)ks * NKTOT + pos0 + row) * HD + n0 + col]) = v;
      }
    }
  }
}

// ---------------------------------------------------------------- combine
__global__ void combine_k(const ushort_t* __restrict__ ybuf, const int* __restrict__ tk_e,
                          const int* __restrict__ tk_s, const float* __restrict__ tk_w,
                          const int* __restrict__ offsets, const float* __restrict__ b2,
                          float* __restrict__ out) {
  const int t = blockIdx.x;
  const int e0 = tk_e[2 * t], e1 = tk_e[2 * t + 1];
  const size_t p0 = (size_t)offsets[e0] + tk_s[2 * t];
  const size_t p1 = (size_t)offsets[e1] + tk_s[2 * t + 1];
  const float w0 = tk_w[2 * t], w1v = tk_w[2 * t + 1];
  const int h = threadIdx.x * 4;
  f32x4 s0 = *reinterpret_cast<const f32x4*>(b2 + (size_t)e0 * HD + h);
  f32x4 s1 = *reinterpret_cast<const f32x4*>(b2 + (size_t)e1 * HD + h);
#pragma unroll
  for (int ks = 0; ks < 2; ++ks) {
    const u16x4 a = *reinterpret_cast<const u16x4*>(
        &ybuf[((size_t)ks * NKTOT + p0) * HD + h]);
    const u16x4 b = *reinterpret_cast<const u16x4*>(
        &ybuf[((size_t)ks * NKTOT + p1) * HD + h]);
    s0.x += bf2f(a.x); s0.y += bf2f(a.y); s0.z += bf2f(a.z); s0.w += bf2f(a.w);
    s1.x += bf2f(b.x); s1.y += bf2f(b.y); s1.z += bf2f(b.z); s1.w += bf2f(b.w);
  }
  f32x4 o = s0 * w0 + s1 * w1v;
  *reinterpret_cast<f32x4*>(out + (size_t)t * HD + h) = o;
}

// ---------------------------------------------------------------- launch
extern "C" void kernel_launch(void* const* d_in, const int* in_sizes, int n_in,
                              void* d_out, int out_size, void* d_ws, size_t ws_size,
                              hipStream_t stream) {
  const float* x  = (const float*)d_in[0];
  const float* rw = (const float*)d_in[1];
  const float* w1 = (const float*)d_in[2];
  const float* b1 = (const float*)d_in[3];
  const float* w2 = (const float*)d_in[4];
  const float* b2 = (const float*)d_in[5];
  float* out = (float*)d_out;

  char* ws = (char*)d_ws;
  ushort_t* Xbf  = (ushort_t*)(ws + 0);            //   8,388,608
  ushort_t* midb = (ushort_t*)(ws + 8388608);      //  67,108,864  [NKTOT][F] bf16
  ushort_t* ybuf = (ushort_t*)(ws + 75497472);     //  33,554,432  [2][NKTOT][H] bf16
  char* sm = ws + 209715200;
  int*   counts  = (int*)(sm);
  int*   offsets = (int*)(sm + 64);
  float* tokP    = (float*)(sm + 128);             // [NTOK][NE]
  int*   tk_e    = (int*)(sm + 128 + 131072);
  int*   tk_s    = (int*)(sm + 128 + 131072 + 32768);
  float* tk_w    = (float*)(sm + 128 + 131072 + 65536);
  int*   slot_token = (int*)(sm + 128 + 131072 + 98304);

  init_k<<<1, 64, 0, stream>>>(counts);
  router_k<<<1024, 256, 0, stream>>>(x, rw, Xbf, tokP, counts, tk_e, tk_s, tk_w);
  finalize_k<<<1, 1024, 0, stream>>>(tokP, counts, offsets, out + (size_t)NTOK * HD);
  build_slots_k<<<32, 256, 0, stream>>>(tk_e, tk_s, offsets, slot_token);
  // G1 grid: e(8) x [np(32) x ty(10)] = 2560 blocks
  moe_fused<true><<<2560, 512, 0, stream>>>(
      Xbf, w1, b1, counts, offsets, slot_token, midb, (ushort_t*)nullptr);
  // G2 grid: e(8) x [np(8) x ks(2) x ty(10)] = 1280 blocks
  moe_fused<false><<<1280, 512, 0, stream>>>(
      midb, w2, b2, counts, offsets, slot_token, (ushort_t*)nullptr, ybuf);
  combine_k<<<4096, 256, 0, stream>>>(ybuf, tk_e, tk_s, tk_w, offsets, b2, out);
}

// Round 14
// 414.471 us; speedup vs baseline: 1.2046x; 1.2046x over previous
//
#include <hip/hip_runtime.h>

// MoE MLP (B=2,T=2048,H=1024,E=8,F=4096,K=2), fp32 in/out.
// route -> one-time weight transpose+bf16 convert (tconv, streamed once) ->
// grouped GEMMs in the m97 structure: 128x128 tile, 4 waves, BK=64, BOTH
// operands global_load_lds into 32KB single-buffered LDS, drain rhythm,
// 4 blocks/CU cover the exposed latency -> weighted combine.
// G2 = split-K2 with bf16 partials (summed with b2 in combine).

typedef unsigned short ushort_t;
typedef __attribute__((ext_vector_type(4))) unsigned int u32x4;
typedef __attribute__((ext_vector_type(4))) unsigned short u16x4;
typedef __attribute__((ext_vector_type(4))) float f32x4;
typedef __attribute__((ext_vector_type(8))) __bf16 bf16x8;

#define NTOK 4096   // B*T
#define HD   1024
#define FD   4096
#define NE   8
#define NKTOT 8192  // NTOK * TOP_K

__device__ __forceinline__ ushort_t f2bf(float f) {
  unsigned u = __builtin_bit_cast(unsigned, f);
  u += 0x7fffu + ((u >> 16) & 1u);   // RNE
  return (ushort_t)(u >> 16);
}
__device__ __forceinline__ float bf2f(ushort_t u) {
  unsigned v = ((unsigned)u) << 16;
  return __builtin_bit_cast(float, v);
}
__device__ __forceinline__ bf16x8 frag_ld(const void* p) {
  u32x4 v = *reinterpret_cast<const u32x4*>(p);
  return __builtin_bit_cast(bf16x8, v);
}

#define GLOAD16(g, l) __builtin_amdgcn_global_load_lds(                         \
    (const __attribute__((address_space(1))) unsigned int*)(g),                 \
    (__attribute__((address_space(3))) unsigned int*)(l), 16, 0, 0)

#define WAITVM0() asm volatile("s_waitcnt vmcnt(0)" ::: "memory")
#define BARRIER() do { asm volatile("s_waitcnt lgkmcnt(0)" ::: "memory");       \
                       __builtin_amdgcn_s_barrier(); } while (0)

// ---------------------------------------------------------------- init
__global__ void init_k(int* counts) {
  if (threadIdx.x < NE) counts[threadIdx.x] = 0;
}

// --------------------------- transpose+convert: src[z][R][C] -> dst[z][C][R]
// (r2-proven vectorized version: f32x4 in, u16x4 out)
__global__ void tconv_k(const float* __restrict__ src, ushort_t* __restrict__ dst,
                        int R, int C) {
  __shared__ float tile[64][65];
  const size_t zb = (size_t)blockIdx.z * R * C;
  const int r0 = blockIdx.y * 64, c0 = blockIdx.x * 64;
  const int tid = threadIdx.x;
  const int rl = tid >> 4, c4 = (tid & 15) * 4;
#pragma unroll
  for (int i = 0; i < 4; ++i) {
    const int r = rl + i * 16;
    const f32x4 v = *reinterpret_cast<const f32x4*>(src + zb + (size_t)(r0 + r) * C + c0 + c4);
    tile[r][c4 + 0] = v.x; tile[r][c4 + 1] = v.y;
    tile[r][c4 + 2] = v.z; tile[r][c4 + 3] = v.w;
  }
  __syncthreads();
  const int rr0 = (tid & 15) * 4, ccl = tid >> 4;
#pragma unroll
  for (int i = 0; i < 4; ++i) {
    const int cc = ccl + i * 16;
    u16x4 o;
    o.x = f2bf(tile[rr0 + 0][cc]); o.y = f2bf(tile[rr0 + 1][cc]);
    o.z = f2bf(tile[rr0 + 2][cc]); o.w = f2bf(tile[rr0 + 3][cc]);
    *reinterpret_cast<u16x4*>(dst + zb + (size_t)(c0 + cc) * R + r0 + rr0) = o;
  }
}

// ------------------------------------------- router (+ fused x->bf16 conv)
__global__ void router_k(const float* __restrict__ x, const float* __restrict__ rw,
                         ushort_t* __restrict__ Xbf,
                         float* __restrict__ tokP, int* __restrict__ counts,
                         int* __restrict__ tk_e, int* __restrict__ tk_s,
                         float* __restrict__ tk_w) {
  const int w = threadIdx.x >> 6, l = threadIdx.x & 63;
  const int t = blockIdx.x * 4 + w;
  const float* xr = x + (size_t)t * HD;
  ushort_t* xo = Xbf + (size_t)t * HD;
  float acc[NE];
#pragma unroll
  for (int e = 0; e < NE; ++e) acc[e] = 0.f;
  for (int it = 0; it < HD / 64; ++it) {
    const int h = l + it * 64;
    const float xv = xr[h];
    xo[h] = f2bf(xv);
#pragma unroll
    for (int e = 0; e < NE; ++e) acc[e] = fmaf(xv, rw[e * HD + h], acc[e]);
  }
#pragma unroll
  for (int e = 0; e < NE; ++e) {
#pragma unroll
    for (int s = 32; s > 0; s >>= 1) acc[e] += __shfl_xor(acc[e], s, 64);
  }
  float m = acc[0];
#pragma unroll
  for (int e = 1; e < NE; ++e) m = fmaxf(m, acc[e]);
  float ssum = 0.f;
  float p[NE];
#pragma unroll
  for (int e = 0; e < NE; ++e) { p[e] = expf(acc[e] - m); ssum += p[e]; }
  const float inv = 1.f / ssum;
  if (l < NE) tokP[(size_t)t * NE + l] = p[l] * inv;

  if (l == 0) {
    int i0 = 0; float v0 = acc[0];
#pragma unroll
    for (int e = 1; e < NE; ++e) if (acc[e] > v0) { v0 = acc[e]; i0 = e; }
    int i1 = -1; float v1 = -3.4e38f;
#pragma unroll
    for (int e = 0; e < NE; ++e) if (e != i0 && acc[e] > v1) { v1 = acc[e]; i1 = e; }
    const float w0 = 1.f / (1.f + expf(v1 - v0));
    const int s0 = atomicAdd(&counts[i0], 1);
    const int s1 = atomicAdd(&counts[i1], 1);
    tk_e[2 * t] = i0;     tk_s[2 * t] = s0;     tk_w[2 * t] = w0;
    tk_e[2 * t + 1] = i1; tk_s[2 * t + 1] = s1; tk_w[2 * t + 1] = 1.f - w0;
  }
}

// ------------------------------------------- offsets + aux loss + tail out
__global__ void finalize_k(const float* __restrict__ tokP, const int* __restrict__ counts,
                           int* __restrict__ offsets, float* __restrict__ out_tail) {
  __shared__ float red[16][8];
  const int tid = threadIdx.x;  // 1024
  f32x4 a0 = {0.f, 0.f, 0.f, 0.f}, a1 = {0.f, 0.f, 0.f, 0.f};
#pragma unroll
  for (int k = 0; k < 4; ++k) {
    const float* p = tokP + ((size_t)tid * 4 + k) * 8;
    a0 += *reinterpret_cast<const f32x4*>(p);
    a1 += *reinterpret_cast<const f32x4*>(p + 4);
  }
#pragma unroll
  for (int s = 1; s < 64; s <<= 1) {
#pragma unroll
    for (int c = 0; c < 4; ++c) {
      a0[c] += __shfl_xor(a0[c], s, 64);
      a1[c] += __shfl_xor(a1[c], s, 64);
    }
  }
  if ((tid & 63) == 0) {
    const int wv = tid >> 6;
#pragma unroll
    for (int c = 0; c < 4; ++c) { red[wv][c] = a0[c]; red[wv][4 + c] = a1[c]; }
  }
  __syncthreads();
  if (tid == 0) {
    float P[8];
    for (int c = 0; c < 8; ++c) {
      float s = 0.f;
      for (int q = 0; q < 16; ++q) s += red[q][c];
      P[c] = s * (1.f / NTOK);
    }
    int off = 0; float aux = 0.f;
    for (int q = 0; q < NE; ++q) { offsets[q] = off; off += counts[q]; }
    for (int q = 0; q < NE; ++q) aux += ((float)counts[q] / (float)NKTOT) * P[q];
    out_tail[0] = (float)NE * aux;
    out_tail[1] = 0.f;
  }
}

// ---------------------------------------------------------------- slots
__global__ void build_slots_k(const int* __restrict__ tk_e, const int* __restrict__ tk_s,
                              const int* __restrict__ offsets, int* __restrict__ slot_token) {
  const int i = blockIdx.x * 256 + threadIdx.x;  // < NKTOT
  const int e = tk_e[i];
  slot_token[offsets[e] + tk_s[i]] = i >> 1;
}

// ------ grouped GEMM, m97 structure: both operands global_load_lds ---------
// 256 thr = 4 waves (2M x 2N, 64x64 each, acc 4x4).  LDS 32KB single-buffered
// (As 16KB + Bs 16KB) -> 4 blocks/CU (launch_bounds cap), cross-block TLP
// covers the per-step drain (m97 mechanism, 37% MfmaUtil at this shape).
// Staging (r1-proven): row = c*32 + w*8 + (l>>3), slot l&7, pre-swizzled
// source chunk (l&7)^(row&7); frag read chunk = kc ^ (l&7).  B = BT[e] rows
// (bf16, k-contiguous) staged identically to A.
// Per step: 4 gload_lds A + 4 gload_lds B; vmcnt(0); barrier; compute
// (2kk x {8 ds_read_b128 + 16 MFMA}); barrier.
// G1: mid = gelu(X@w1+b1) bf16.  G2: bf16 k-slice partials (ks=2, K=2048).
template <bool IS_G1>
__global__ __launch_bounds__(256, 4) void moe_gemm(
    const ushort_t* __restrict__ A, const ushort_t* __restrict__ BT,
    const float* __restrict__ bias,
    const int* __restrict__ counts, const int* __restrict__ offsets,
    const int* __restrict__ slot_token,
    ushort_t* __restrict__ midout, ushort_t* __restrict__ ybuf) {
  constexpr int KDF = IS_G1 ? HD : FD;   // A / BT row stride (elems)
  constexpr int ND  = IS_G1 ? FD : HD;   // BT rows per expert
  constexpr int NSTEP = IS_G1 ? 16 : 32;
  const int id = blockIdx.x;
  const int e = id & 7;                  // XCD pin
  const int q = id >> 3;
  const int ty = q % 10;                 // ty-inner: same-panel blocks cluster
  const int r = q / 10;
  const int np = IS_G1 ? r : (r >> 1);
  const int ks = IS_G1 ? 0 : (r & 1);
  const int n0 = np * 128;
  const int KB = ks * 2048;              // k window base (elems)
  const int cnt = counts[e];
  if (ty * 128 >= cnt) return;
  const int off = offsets[e];
  const int pos0 = off + ty * 128;
  const int rr = cnt - ty * 128;
  const int rows_rem = rr < 128 ? rr : 128;

  // As = lds[0..8191], Bs = lds[8192..16383]  (32 KB)
  __shared__ __align__(16) ushort_t lds[16384];

  const int tid = threadIdx.x;
  const int w = tid >> 6, l = tid & 63;
  const int wr = w >> 1, wc = w & 1;     // 2 (M) x 2 (N) waves, 64x64 each

  // ---- staging addresses (pre-swizzled source, linear LDS dest)
  const int sw = (((l & 7) ^ ((l >> 3) & 7)) << 4);
  const char* aptr[4];
  const char* bptr[4];
#pragma unroll
  for (int c = 0; c < 4; ++c) {
    const int row = c * 32 + w * 8 + (l >> 3);
    int pos = pos0 + row; if (pos > NKTOT - 1) pos = NKTOT - 1;
    const size_t ar = IS_G1 ? (size_t)slot_token[pos] : (size_t)pos;
    aptr[c] = (const char*)A + (ar * KDF + KB) * 2 + sw;
    const int rb = n0 + row;
    bptr[c] = (const char*)BT + (((size_t)e * ND + rb) * KDF + KB) * 2 + sw;
  }

  f32x4 acc[4][4] = {};

  for (int t = 0; t < NSTEP; ++t) {
#pragma unroll
    for (int c = 0; c < 4; ++c)
      GLOAD16(aptr[c] + t * 128, &lds[(c * 32 + w * 8) * 64]);
#pragma unroll
    for (int c = 0; c < 4; ++c)
      GLOAD16(bptr[c] + t * 128, &lds[8192 + (c * 32 + w * 8) * 64]);
    WAITVM0();
    BARRIER();
    {
      const int arow = wr * 64 + (l & 15);
      const int brow = wc * 64 + (l & 15);
      const int key = l & 7;             // = row&7 for both frag rows
#pragma unroll
      for (int kk = 0; kk < 2; ++kk) {
        const int kc = kk * 4 + (l >> 4);
        bf16x8 afr[4];
#pragma unroll
        for (int mm = 0; mm < 4; ++mm)
          afr[mm] = frag_ld(&lds[(arow + mm * 16) * 64 + ((kc ^ key) << 3)]);
        __builtin_amdgcn_s_setprio(1);
#pragma unroll
        for (int nn = 0; nn < 4; ++nn) {
          const bf16x8 bfr =
              frag_ld(&lds[8192 + (brow + nn * 16) * 64 + ((kc ^ key) << 3)]);
#pragma unroll
          for (int mm = 0; mm < 4; ++mm)
            acc[mm][nn] = __builtin_amdgcn_mfma_f32_16x16x32_bf16(
                afr[mm], bfr, acc[mm][nn], 0, 0, 0);
        }
        __builtin_amdgcn_s_setprio(0);
      }
    }
    BARRIER();
  }

  // ---- epilogue: acc -> bf16 via LDS repack, coalesced 16B row stores.
  // C/D: col = l&15, row = 4*(l>>4)+j within each 16x16 frag. (r12-proven)
  {
    const int lr4 = (l >> 4) * 4, lc = l & 15;
#pragma unroll
    for (int nn = 0; nn < 4; ++nn) {
      const int col = wc * 64 + nn * 16 + lc;
      const float bv = IS_G1 ? bias[(size_t)e * FD + n0 + col] : 0.f;
#pragma unroll
      for (int mm = 0; mm < 4; ++mm) {
        const int rb = wr * 64 + mm * 16 + lr4;
#pragma unroll
        for (int j = 0; j < 4; ++j) {
          float v = acc[mm][nn][j] + bv;
          if (IS_G1) v = 0.5f * v * (1.0f + erff(v * 0.70710678118654752f));
          lds[(rb + j) * 128 + col] = f2bf(v);
        }
      }
    }
    BARRIER();
#pragma unroll
    for (int p = 0; p < 8; ++p) {
      const int idx = p * 2048 + tid * 8;
      const int row = idx >> 7;
      const int col = idx & 127;
      if (row < rows_rem) {
        const u32x4 v = *reinterpret_cast<const u32x4*>(&lds[idx]);
        if (IS_G1)
          *reinterpret_cast<u32x4*>(&midout[(size_t)(pos0 + row) * FD + n0 + col]) = v;
        else
          *reinterpret_cast<u32x4*>(
              &ybuf[((size_t)ks * NKTOT + pos0 + row) * HD + n0 + col]) = v;
      }
    }
  }
}

// ---------------------------------------------------------------- combine
__global__ void combine_k(const ushort_t* __restrict__ ybuf, const int* __restrict__ tk_e,
                          const int* __restrict__ tk_s, const float* __restrict__ tk_w,
                          const int* __restrict__ offsets, const float* __restrict__ b2,
                          float* __restrict__ out) {
  const int t = blockIdx.x;
  const int e0 = tk_e[2 * t], e1 = tk_e[2 * t + 1];
  const size_t p0 = (size_t)offsets[e0] + tk_s[2 * t];
  const size_t p1 = (size_t)offsets[e1] + tk_s[2 * t + 1];
  const float w0 = tk_w[2 * t], w1v = tk_w[2 * t + 1];
  const int h = threadIdx.x * 4;
  f32x4 s0 = *reinterpret_cast<const f32x4*>(b2 + (size_t)e0 * HD + h);
  f32x4 s1 = *reinterpret_cast<const f32x4*>(b2 + (size_t)e1 * HD + h);
#pragma unroll
  for (int ks = 0; ks < 2; ++ks) {
    const u16x4 a = *reinterpret_cast<const u16x4*>(
        &ybuf[((size_t)ks * NKTOT + p0) * HD + h]);
    const u16x4 b = *reinterpret_cast<const u16x4*>(
        &ybuf[((size_t)ks * NKTOT + p1) * HD + h]);
    s0.x += bf2f(a.x); s0.y += bf2f(a.y); s0.z += bf2f(a.z); s0.w += bf2f(a.w);
    s1.x += bf2f(b.x); s1.y += bf2f(b.y); s1.z += bf2f(b.z); s1.w += bf2f(b.w);
  }
  f32x4 o = s0 * w0 + s1 * w1v;
  *reinterpret_cast<f32x4*>(out + (size_t)t * HD + h) = o;
}

// ---------------------------------------------------------------- launch
extern "C" void kernel_launch(void* const* d_in, const int* in_sizes, int n_in,
                              void* d_out, int out_size, void* d_ws, size_t ws_size,
                              hipStream_t stream) {
  const float* x  = (const float*)d_in[0];
  const float* rw = (const float*)d_in[1];
  const float* w1 = (const float*)d_in[2];
  const float* b1 = (const float*)d_in[3];
  const float* w2 = (const float*)d_in[4];
  const float* b2 = (const float*)d_in[5];
  float* out = (float*)d_out;

  char* ws = (char*)d_ws;
  ushort_t* Xbf  = (ushort_t*)(ws + 0);            //   8,388,608
  ushort_t* W1T  = (ushort_t*)(ws + 8388608);      //  67,108,864  [E][F][H] bf16
  ushort_t* W2T  = (ushort_t*)(ws + 75497472);     //  67,108,864  [E][H][F] bf16
  ushort_t* midb = (ushort_t*)(ws + 142606336);    //  67,108,864  [NKTOT][F] bf16
  ushort_t* ybuf = (ushort_t*)(ws + 8388608);      //  33,554,432  [2][NKTOT][H], aliases W1T (dead after G1)
  char* sm = ws + 209715200;
  int*   counts  = (int*)(sm);
  int*   offsets = (int*)(sm + 64);
  float* tokP    = (float*)(sm + 128);             // [NTOK][NE]
  int*   tk_e    = (int*)(sm + 128 + 131072);
  int*   tk_s    = (int*)(sm + 128 + 131072 + 32768);
  float* tk_w    = (float*)(sm + 128 + 131072 + 65536);
  int*   slot_token = (int*)(sm + 128 + 131072 + 98304);

  init_k<<<1, 64, 0, stream>>>(counts);
  tconv_k<<<dim3(64, 16, 8), 256, 0, stream>>>(w1, W1T, HD, FD);  // [H][F]->[F][H]
  tconv_k<<<dim3(16, 64, 8), 256, 0, stream>>>(w2, W2T, FD, HD);  // [F][H]->[H][F]
  router_k<<<1024, 256, 0, stream>>>(x, rw, Xbf, tokP, counts, tk_e, tk_s, tk_w);
  finalize_k<<<1, 1024, 0, stream>>>(tokP, counts, offsets, out + (size_t)NTOK * HD);
  build_slots_k<<<32, 256, 0, stream>>>(tk_e, tk_s, offsets, slot_token);
  // G1 grid: e(8) x [np(32) x ty(10)] = 2560 blocks
  moe_gemm<true><<<2560, 256, 0, stream>>>(
      Xbf, W1T, b1, counts, offsets, slot_token, midb, (ushort_t*)nullptr);
  // G2 grid: e(8) x [np(8) x ks(2) x ty(10)] = 1280 blocks
  moe_gemm<false><<<1280, 256, 0, stream>>>(
      midb, W2T, b2, counts, offsets, slot_token, (ushort_t*)nullptr, ybuf);
  combine_k<<<4096, 256, 0, stream>>>(ybuf, tk_e, tk_s, tk_w, offsets, b2, out);
}